// Round 1
// baseline (1230.175 us; speedup 1.0000x reference)
//
#include <hip/hip_runtime.h>

// Problem constants (from reference)
#define NB   32
#define NT   2048
#define ND   512
#define NH   64
#define NS   3
#define NBLKS 2
#define ROW  (2*ND + 1)   // 1025 floats per output row

// One 64-thread block handles 64 (b,t) rows:
//  - cooperatively writes the 2*512 feature columns for those rows (memory-bound)
//  - each thread runs the full normalizing flow for its own row (compute-bound)
// Fused so VMEM stores drain while VALU does the flow matvecs.
__global__ __launch_bounds__(64, 1) void nf_fused(
    const float* __restrict__ trend, const float* __restrict__ seasonal,
    const float* __restrict__ residual,
    const float* __restrict__ Wt, const float* __restrict__ bt,
    const float* __restrict__ Ws, const float* __restrict__ bs,
    const float* __restrict__ b_init, const float* __restrict__ Wc0,
    const float* __restrict__ bc0,
    const float* __restrict__ W1, const float* __restrict__ b1,
    const float* __restrict__ W2, const float* __restrict__ b2,
    const float* __restrict__ Wcb, const float* __restrict__ bcb,
    const float* __restrict__ Wf, const float* __restrict__ bfin,
    float* __restrict__ out)
{
    __shared__ float s_tr[64], s_se[64];
    __shared__ float s_buf[64 * 65];   // stride 65: bank=(lane+m)%32 -> 2-way, free

    const int tid  = threadIdx.x;
    const int row0 = blockIdx.x * 64;
    const int n    = row0 + tid;
    const int t    = n & (NT - 1);

    s_tr[tid] = trend[n];
    s_se[tid] = seasonal[n];
    __syncthreads();

    // ---------------- feature part: 268 MB of coalesced dword stores ----------------
    float wtv[8], btv[8], wsv[8], bsv[8];
    #pragma unroll
    for (int j = 0; j < 8; ++j) {
        wtv[j] = Wt[tid + 64*j];
        btv[j] = bt[tid + 64*j];
        wsv[j] = Ws[tid + 64*j];
        bsv[j] = bs[tid + 64*j];
    }
    for (int r = 0; r < 64; ++r) {
        const float a  = s_tr[r];
        const float sv = s_se[r];
        float* rowp = out + (size_t)(row0 + r) * ROW;
        #pragma unroll
        for (int j = 0; j < 8; ++j) {
            rowp[tid + 64*j]      = fmaf(a,  wtv[j], btv[j]);
            rowp[ND + tid + 64*j] = fmaf(sv, wsv[j], bsv[j]);
        }
    }

    // ---------------- flow part: per-thread MADE flow, weights via s_load ----------------
    const float x = residual[n];
    const float c = (t == 0) ? 0.0f : residual[n - 1];
    float z = x;
    float logdet = 0.0f;
    float* myb = &s_buf[tid * 65];

    #pragma unroll
    for (int i = 0; i < NS; ++i) {
        float h[NH];
        #pragma unroll
        for (int k = 0; k < NH; ++k)
            h[k] = fmaf(c, Wc0[i*NH + k], bc0[i*NH + k] + b_init[i*NH + k]);

        #pragma unroll
        for (int j = 0; j < NBLKS; ++j) {
            const int ij = i * NBLKS + j;
            const float* w1p = W1 + (size_t)ij * NH * NH;
            const float* w2p = W2 + (size_t)ij * NH * NH;

            float v[NH];
            #pragma unroll
            for (int m = 0; m < NH; ++m) v[m] = fmaxf(h[m], 0.0f);

            // t1 = relu(relu(h) @ W1^T + b1) ; rows of W1 are uniform -> s_load_dwordx16
            #pragma unroll 2
            for (int k = 0; k < NH; ++k) {
                const float* wrow = w1p + k * NH;
                float a0 = 0.f, a1 = 0.f, a2 = 0.f, a3 = 0.f;
                #pragma unroll
                for (int m = 0; m < 16; ++m) {
                    a0 = fmaf(v[m],      wrow[m],      a0);
                    a1 = fmaf(v[16+m],   wrow[16+m],   a1);
                    a2 = fmaf(v[32+m],   wrow[32+m],   a2);
                    a3 = fmaf(v[48+m],   wrow[48+m],   a3);
                }
                const float acc = b1[ij*NH + k] + ((a0 + a1) + (a2 + a3));
                myb[k] = fmaxf(acc, 0.0f);   // runtime-k store goes to LDS, not scratch
            }
            #pragma unroll
            for (int m = 0; m < NH; ++m) v[m] = myb[m];

            // t2 = relu(t1) @ W2^T + b2 ; h += t2 * sigmoid(c*Wcb + bcb)
            #pragma unroll 2
            for (int k = 0; k < NH; ++k) {
                const float* wrow = w2p + k * NH;
                float a0 = 0.f, a1 = 0.f, a2 = 0.f, a3 = 0.f;
                #pragma unroll
                for (int m = 0; m < 16; ++m) {
                    a0 = fmaf(v[m],      wrow[m],      a0);
                    a1 = fmaf(v[16+m],   wrow[16+m],   a1);
                    a2 = fmaf(v[32+m],   wrow[32+m],   a2);
                    a3 = fmaf(v[48+m],   wrow[48+m],   a3);
                }
                const float t2v = b2[ij*NH + k] + ((a0 + a1) + (a2 + a3));
                const float g   = fmaf(c, Wcb[ij*NH + k], bcb[ij*NH + k]);
                const float sg  = 1.0f / (1.0f + __expf(-g));
                myb[k] = t2v * sg;
            }
            #pragma unroll
            for (int m = 0; m < NH; ++m) h[m] += myb[m];
        }

        // final Linear(H, 2) -> (unconstrained_scale, shift)
        float o0 = bfin[2*i], o1 = bfin[2*i + 1];
        #pragma unroll
        for (int m = 0; m < NH; ++m) {
            const float r = fmaxf(h[m], 0.0f);
            o0 = fmaf(r, Wf[(2*i)   * NH + m], o0);
            o1 = fmaf(r, Wf[(2*i+1) * NH + m], o1);
        }
        const float sp = log1pf(__expf(o0)) + 1e-3f;   // softplus + 1e-3
        z = fmaf(sp, z, o1);
        logdet += __logf(sp);
    }

    // log_prob = -0.5 z^2 - 0.5 log(2pi) + logdet
    out[(size_t)n * ROW + 2*ND] = fmaf(-0.5f, z * z, logdet) - 0.91893853320467274178f;
}

extern "C" void kernel_launch(void* const* d_in, const int* in_sizes, int n_in,
                              void* d_out, int out_size, void* d_ws, size_t ws_size,
                              hipStream_t stream) {
    const float* trend    = (const float*)d_in[0];
    const float* seasonal = (const float*)d_in[1];
    const float* residual = (const float*)d_in[2];
    const float* Wt       = (const float*)d_in[3];
    const float* bt       = (const float*)d_in[4];
    const float* Ws       = (const float*)d_in[5];
    const float* bs       = (const float*)d_in[6];
    const float* b_init   = (const float*)d_in[7];
    const float* Wc0      = (const float*)d_in[8];
    const float* bc0      = (const float*)d_in[9];
    const float* W1       = (const float*)d_in[10];
    const float* b1       = (const float*)d_in[11];
    const float* W2       = (const float*)d_in[12];
    const float* b2       = (const float*)d_in[13];
    const float* Wcb      = (const float*)d_in[14];
    const float* bcb      = (const float*)d_in[15];
    const float* Wf       = (const float*)d_in[16];
    const float* bfin     = (const float*)d_in[17];
    float* out            = (float*)d_out;

    const int nrows = NB * NT;           // 65536
    dim3 grid(nrows / 64), block(64);    // 1024 blocks x 1 wave
    hipLaunchKernelGGL(nf_fused, grid, block, 0, stream,
                       trend, seasonal, residual, Wt, bt, Ws, bs,
                       b_init, Wc0, bc0, W1, b1, W2, b2, Wcb, bcb, Wf, bfin, out);
}

// Round 2
// 355.332 us; speedup vs baseline: 3.4620x; 3.4620x over previous
//
#include <hip/hip_runtime.h>

#define NB 32
#define NT 2048
#define ND 512
#define NH 64
#define NS 3
#define NBLKS 2
#define ROWLEN (2*ND + 1)   // 1025 floats per output row

typedef __attribute__((ext_vector_type(8))) short bf16x8;   // 8 bf16 = 4 VGPR (guide §3)
typedef float f32x4 __attribute__((ext_vector_type(4)));

// bf16 packed-weight workspace layout (ushort elements)
#define W1_OFF 0
#define W2_OFF 24576
#define WF_OFF 49152
#define WS_ELEMS 52224      // = 104448 bytes

__device__ __forceinline__ unsigned int f2bf(float f) {      // RNE f32->bf16
    unsigned int u = __float_as_uint(f);
    return (u + 0x7FFFu + ((u >> 16) & 1u)) >> 16;
}
__device__ __forceinline__ unsigned int pack2(float a, float b) {
    return f2bf(a) | (f2bf(b) << 16);
}

// One-shot (per launch) f32 -> bf16 weight conversion into d_ws.
// W1,W2: [S][NBLK][64][64] flat. Wf: [S][2][64] -> padded [S][16][64] (rows>=2 zero).
__global__ __launch_bounds__(256) void prepack(
    const float* __restrict__ W1, const float* __restrict__ W2,
    const float* __restrict__ Wf, unsigned short* __restrict__ ws)
{
    int idx = blockIdx.x * 256 + threadIdx.x;
    if (idx < 24576) {
        ws[W1_OFF + idx] = (unsigned short)f2bf(W1[idx]);
    } else if (idx < 49152) {
        int o = idx - 24576;
        ws[W2_OFF + o] = (unsigned short)f2bf(W2[o]);
    } else if (idx < WS_ELEMS) {
        int o = idx - 49152;                 // [3][16][64]
        int s = o >> 10, row = (o >> 6) & 15, m = o & 63;
        float v = (row < 2) ? Wf[s * 128 + row * 64 + m] : 0.0f;
        ws[WF_OFF + o] = (unsigned short)f2bf(v);
    }
}

// Block = 256 threads (4 waves) handles 64 rows.
//  - feature part: 64 rows x 1024 coalesced f32 stores (the HBM floor), issued first
//  - flow part: each wave runs 16 rows through the MADE flow with bf16 MFMA.
//    Orientation D[k_out][sample] = W . act^T so h/gate/D all share lane layout:
//    lane: sample r = lane&15, unit block q = lane>>4; lane owns units 16t+4q+i.
__global__ __launch_bounds__(256, 4) void nf_main(
    const float* __restrict__ trend, const float* __restrict__ seasonal,
    const float* __restrict__ residual,
    const float* __restrict__ Wt, const float* __restrict__ bt,
    const float* __restrict__ Ws, const float* __restrict__ bs,
    const float* __restrict__ b_init, const float* __restrict__ Wc0,
    const float* __restrict__ bc0,
    const float* __restrict__ b1, const float* __restrict__ b2,
    const float* __restrict__ Wcb, const float* __restrict__ bcb,
    const float* __restrict__ bf_, const unsigned short* __restrict__ wpk,
    float* __restrict__ out)
{
    __shared__ float s_tr[64], s_se[64];
    __shared__ unsigned short s_X[4][16][72];   // per-wave act tile, stride 72 bf16 (2-way banks = free)

    const int tid  = threadIdx.x;
    const int row0 = blockIdx.x * 64;

    if (tid < 64) { s_tr[tid] = trend[row0 + tid]; s_se[tid] = seasonal[row0 + tid]; }
    __syncthreads();

    // ---------- feature part: fire-and-forget stores ----------
    {
        float wv[4], bv[4];
        #pragma unroll
        for (int j = 0; j < 4; ++j) {
            int cc = tid + 256 * j;
            if (cc < ND) { wv[j] = Wt[cc];      bv[j] = bt[cc]; }
            else         { wv[j] = Ws[cc - ND]; bv[j] = bs[cc - ND]; }
        }
        for (int rr = 0; rr < 64; ++rr) {
            float a = s_tr[rr], sv = s_se[rr];
            float* rp = out + (size_t)(row0 + rr) * ROWLEN;
            #pragma unroll
            for (int j = 0; j < 4; ++j) {
                int cc = tid + 256 * j;
                rp[cc] = fmaf((cc < ND) ? a : sv, wv[j], bv[j]);
            }
        }
    }

    // ---------- flow part ----------
    const int lane = tid & 63;
    const int wv_  = tid >> 6;
    const int r    = lane & 15;      // sample within wave tile; also A-frag row, D col
    const int q    = lane >> 4;      // k-quad
    const int n    = row0 + wv_ * 16 + r;
    const float x  = residual[n];
    const float c  = ((n & (NT - 1)) == 0) ? 0.0f : residual[n - 1];
    unsigned short (* const X)[72] = s_X[wv_];
    const int u0 = 4 * q;            // unit = 16*t + u0 + e

    float z = x, logdet = 0.0f;

    for (int i = 0; i < NS; ++i) {
        float h[4][4];
        #pragma unroll
        for (int t = 0; t < 4; ++t) {
            const int ub = i * NH + 16 * t + u0;
            const f32x4 wc  = *(const f32x4*)(Wc0 + ub);
            const f32x4 b0v = *(const f32x4*)(bc0 + ub);
            const f32x4 biv = *(const f32x4*)(b_init + ub);
            #pragma unroll
            for (int e = 0; e < 4; ++e) h[t][e] = fmaf(c, wc[e], b0v[e] + biv[e]);
        }

        for (int j = 0; j < NBLKS; ++j) {
            const int ij = i * NBLKS + j;
            // write relu(h) -> LDS (B operand for W1 matvec)
            #pragma unroll
            for (int t = 0; t < 4; ++t) {
                uint2 p;
                p.x = pack2(fmaxf(h[t][0], 0.f), fmaxf(h[t][1], 0.f));
                p.y = pack2(fmaxf(h[t][2], 0.f), fmaxf(h[t][3], 0.f));
                *(uint2*)&X[r][16 * t + u0] = p;
            }
            __syncthreads();   // cross-lane RAW: write-phase -> read-phase

            f32x4 D[4];
            {   // t1 = relu(h) @ W1^T
                const unsigned short* Wb = wpk + W1_OFF + ij * 4096;
                bf16x8 bA = *(const bf16x8*)&X[r][8 * q];
                bf16x8 bB = *(const bf16x8*)&X[r][32 + 8 * q];
                #pragma unroll
                for (int t = 0; t < 4; ++t) {
                    bf16x8 a0 = *(const bf16x8*)&Wb[(16 * t + r) * 64 + 8 * q];
                    bf16x8 a1 = *(const bf16x8*)&Wb[(16 * t + r) * 64 + 32 + 8 * q];
                    f32x4 d = {0.f, 0.f, 0.f, 0.f};
                    d = __builtin_amdgcn_mfma_f32_16x16x32_bf16(a0, bA, d, 0, 0, 0);
                    d = __builtin_amdgcn_mfma_f32_16x16x32_bf16(a1, bB, d, 0, 0, 0);
                    D[t] = d;
                }
            }
            // t1 = relu(D + b1) -> LDS  (writes depend on D -> ordered after reads)
            #pragma unroll
            for (int t = 0; t < 4; ++t) {
                const f32x4 bb = *(const f32x4*)(b1 + ij * NH + 16 * t + u0);
                uint2 p;
                p.x = pack2(fmaxf(D[t][0] + bb[0], 0.f), fmaxf(D[t][1] + bb[1], 0.f));
                p.y = pack2(fmaxf(D[t][2] + bb[2], 0.f), fmaxf(D[t][3] + bb[3], 0.f));
                *(uint2*)&X[r][16 * t + u0] = p;
            }
            __syncthreads();

            {   // t2 = t1 @ W2^T
                const unsigned short* Wb = wpk + W2_OFF + ij * 4096;
                bf16x8 bA = *(const bf16x8*)&X[r][8 * q];
                bf16x8 bB = *(const bf16x8*)&X[r][32 + 8 * q];
                #pragma unroll
                for (int t = 0; t < 4; ++t) {
                    bf16x8 a0 = *(const bf16x8*)&Wb[(16 * t + r) * 64 + 8 * q];
                    bf16x8 a1 = *(const bf16x8*)&Wb[(16 * t + r) * 64 + 32 + 8 * q];
                    f32x4 d = {0.f, 0.f, 0.f, 0.f};
                    d = __builtin_amdgcn_mfma_f32_16x16x32_bf16(a0, bA, d, 0, 0, 0);
                    d = __builtin_amdgcn_mfma_f32_16x16x32_bf16(a1, bB, d, 0, 0, 0);
                    D[t] = d;
                }
            }
            // h += (t2 + b2) * sigmoid(c*Wcb + bcb)
            #pragma unroll
            for (int t = 0; t < 4; ++t) {
                const int ub = ij * NH + 16 * t + u0;
                const f32x4 b2v = *(const f32x4*)(b2 + ub);
                const f32x4 wg  = *(const f32x4*)(Wcb + ub);
                const f32x4 bg  = *(const f32x4*)(bcb + ub);
                #pragma unroll
                for (int e = 0; e < 4; ++e) {
                    float g  = fmaf(c, wg[e], bg[e]);
                    float sg = 1.0f / (1.0f + __expf(-g));
                    h[t][e] += (D[t][e] + b2v[e]) * sg;
                }
            }
        }

        // final Linear(H,2) via padded-Wf MFMA: D rows 0/1 = (o0,o1) on q==0 lanes
        #pragma unroll
        for (int t = 0; t < 4; ++t) {
            uint2 p;
            p.x = pack2(fmaxf(h[t][0], 0.f), fmaxf(h[t][1], 0.f));
            p.y = pack2(fmaxf(h[t][2], 0.f), fmaxf(h[t][3], 0.f));
            *(uint2*)&X[r][16 * t + u0] = p;
        }
        __syncthreads();
        {
            const unsigned short* Wb = wpk + WF_OFF + i * 1024;
            bf16x8 bA = *(const bf16x8*)&X[r][8 * q];
            bf16x8 bB = *(const bf16x8*)&X[r][32 + 8 * q];
            bf16x8 a0 = *(const bf16x8*)&Wb[r * 64 + 8 * q];
            bf16x8 a1 = *(const bf16x8*)&Wb[r * 64 + 32 + 8 * q];
            f32x4 d = {0.f, 0.f, 0.f, 0.f};
            d = __builtin_amdgcn_mfma_f32_16x16x32_bf16(a0, bA, d, 0, 0, 0);
            d = __builtin_amdgcn_mfma_f32_16x16x32_bf16(a1, bB, d, 0, 0, 0);
            float o0 = d[0] + bf_[2 * i];
            float o1 = d[1] + bf_[2 * i + 1];
            float sp = log1pf(__expf(o0)) + 1e-3f;   // softplus + 1e-3
            z = fmaf(sp, z, o1);
            logdet += __logf(sp);
        }
        __syncthreads();   // protect next-step LDS writes vs this step's reads (no data dep)
    }

    if (q == 0)
        out[(size_t)n * ROWLEN + 2 * ND] = fmaf(-0.5f, z * z, logdet) - 0.91893853320467274178f;
}

extern "C" void kernel_launch(void* const* d_in, const int* in_sizes, int n_in,
                              void* d_out, int out_size, void* d_ws, size_t ws_size,
                              hipStream_t stream) {
    const float* trend    = (const float*)d_in[0];
    const float* seasonal = (const float*)d_in[1];
    const float* residual = (const float*)d_in[2];
    const float* Wt       = (const float*)d_in[3];
    const float* bt       = (const float*)d_in[4];
    const float* Ws       = (const float*)d_in[5];
    const float* bs       = (const float*)d_in[6];
    const float* b_init   = (const float*)d_in[7];
    const float* Wc0      = (const float*)d_in[8];
    const float* bc0      = (const float*)d_in[9];
    const float* W1       = (const float*)d_in[10];
    const float* b1       = (const float*)d_in[11];
    const float* W2       = (const float*)d_in[12];
    const float* b2       = (const float*)d_in[13];
    const float* Wcb      = (const float*)d_in[14];
    const float* bcb      = (const float*)d_in[15];
    const float* Wf       = (const float*)d_in[16];
    const float* bfin     = (const float*)d_in[17];
    float* out            = (float*)d_out;
    unsigned short* wpk   = (unsigned short*)d_ws;

    hipLaunchKernelGGL(prepack, dim3(WS_ELEMS / 256), dim3(256), 0, stream, W1, W2, Wf, wpk);

    const int nrows = NB * NT;                    // 65536
    hipLaunchKernelGGL(nf_main, dim3(nrows / 64), dim3(256), 0, stream,
                       trend, seasonal, residual, Wt, bt, Ws, bs,
                       b_init, Wc0, bc0, b1, b2, Wcb, bcb, bfin, wpk, out);
}